// Round 3
// baseline (876.743 us; speedup 1.0000x reference)
//
#include <hip/hip_runtime.h>
#include <math.h>

#define DD  128   // node channels (in == out == hidden)
#define DEE 32    // edge channels

// =====================================================================
// Generic fused GEMM: out[n][c] = post( sum_k pre(in[n][k]) * W[k][c] + bias[c] )
//   PRE: 0 = identity, 1 = GIN ((1+eps)*h + U/denom), 2 = BN (tanh(z*a+b))
//   POST: 0 = identity, 1 = tanh
//   BNSTAT: accumulate per-channel sum/sumsq of raw output into bnsum/bnsumsq
// Weights are 128x128, staged fully in LDS. 16-row input tiles.
// Each thread: 2 rows x 4 consecutive cols.
// =====================================================================
template<int PRE, int POST, int BNSTAT>
__global__ __launch_bounds__(256) void gemm128_kernel(
    const float* __restrict__ in, const float* __restrict__ W,
    const float* __restrict__ bias, float* __restrict__ out, int nrows,
    const float* __restrict__ U, const float* __restrict__ denom,
    const float* __restrict__ epsp,
    const float* __restrict__ bnscale, const float* __restrict__ bnshift,
    float* __restrict__ bnsum, float* __restrict__ bnsumsq)
{
    __shared__ float Ws[DD * DD];      // 64 KB
    __shared__ float Xs[16 * DD];      // 8 KB
    __shared__ float as_[DD], bs_[DD]; // BN scale/shift
    __shared__ float ps[DD], psq[DD];  // BN-stat partials

    const int tid = threadIdx.x;

    for (int i = tid; i < DD * DD / 4; i += 256)
        ((float4*)Ws)[i] = ((const float4*)W)[i];
    if constexpr (PRE == 2) {
        if (tid < DD) { as_[tid] = bnscale[tid]; bs_[tid] = bnshift[tid]; }
    }
    if constexpr (BNSTAT != 0) {
        if (tid < DD) { ps[tid] = 0.f; psq[tid] = 0.f; }
    }
    float epsv = 1.0f;
    if constexpr (PRE == 1) epsv = 1.0f + epsp[0];
    __syncthreads();

    const int c0 = (tid & 31) * 4;  // col quad
    const int r0 = tid >> 5;        // 0..7 (rows r0 and r0+8)
    float bsum0=0.f,bsum1=0.f,bsum2=0.f,bsum3=0.f;
    float bsq0=0.f,bsq1=0.f,bsq2=0.f,bsq3=0.f;

    const int ntiles = (nrows + 15) >> 4;
    for (int tile = blockIdx.x; tile < ntiles; tile += gridDim.x) {
        const int row_base = tile << 4;

        // ---- stage 16x128 input tile (8 elements per thread) ----
        {
            const int idx = tid * 8;
            const int r   = idx >> 7;
            const int k0  = idx & 127;
            const int row = row_base + r;
            float4 v0 = make_float4(0.f,0.f,0.f,0.f);
            float4 v1 = make_float4(0.f,0.f,0.f,0.f);
            if (row < nrows) {
                const float* ip = in + (size_t)row * DD + k0;
                float4 a0 = *(const float4*)ip;
                float4 a1 = *(const float4*)(ip + 4);
                if constexpr (PRE == 0) {
                    v0 = a0; v1 = a1;
                } else if constexpr (PRE == 1) {
                    const float invd = 1.0f / (denom[row] + 1e-16f);
                    const float* up = U + (size_t)row * DD + k0;
                    float4 u0 = *(const float4*)up;
                    float4 u1 = *(const float4*)(up + 4);
                    v0.x = epsv*a0.x + u0.x*invd;  v0.y = epsv*a0.y + u0.y*invd;
                    v0.z = epsv*a0.z + u0.z*invd;  v0.w = epsv*a0.w + u0.w*invd;
                    v1.x = epsv*a1.x + u1.x*invd;  v1.y = epsv*a1.y + u1.y*invd;
                    v1.z = epsv*a1.z + u1.z*invd;  v1.w = epsv*a1.w + u1.w*invd;
                } else {
                    v0.x = tanhf(a0.x*as_[k0+0] + bs_[k0+0]);
                    v0.y = tanhf(a0.y*as_[k0+1] + bs_[k0+1]);
                    v0.z = tanhf(a0.z*as_[k0+2] + bs_[k0+2]);
                    v0.w = tanhf(a0.w*as_[k0+3] + bs_[k0+3]);
                    v1.x = tanhf(a1.x*as_[k0+4] + bs_[k0+4]);
                    v1.y = tanhf(a1.y*as_[k0+5] + bs_[k0+5]);
                    v1.z = tanhf(a1.z*as_[k0+6] + bs_[k0+6]);
                    v1.w = tanhf(a1.w*as_[k0+7] + bs_[k0+7]);
                }
            }
            *(float4*)&Xs[idx]     = v0;
            *(float4*)&Xs[idx + 4] = v1;
        }
        __syncthreads();

        float acc00=0,acc01=0,acc02=0,acc03=0;
        float acc10=0,acc11=0,acc12=0,acc13=0;
        #pragma unroll 4
        for (int k = 0; k < DD; k += 4) {
            float4 x0 = *(const float4*)&Xs[r0 * DD + k];
            float4 x1 = *(const float4*)&Xs[(r0 + 8) * DD + k];
            const float xs0[4] = {x0.x, x0.y, x0.z, x0.w};
            const float xs1[4] = {x1.x, x1.y, x1.z, x1.w};
            #pragma unroll
            for (int kk = 0; kk < 4; kk++) {
                float4 wv = *(const float4*)&Ws[(k + kk) * DD + c0];
                acc00 += xs0[kk]*wv.x; acc01 += xs0[kk]*wv.y;
                acc02 += xs0[kk]*wv.z; acc03 += xs0[kk]*wv.w;
                acc10 += xs1[kk]*wv.x; acc11 += xs1[kk]*wv.y;
                acc12 += xs1[kk]*wv.z; acc13 += xs1[kk]*wv.w;
            }
        }

        // ---- epilogue ----
        float4 bv = make_float4(0.f,0.f,0.f,0.f);
        if (bias) bv = *(const float4*)(bias + c0);
        float o00 = acc00 + bv.x, o01 = acc01 + bv.y, o02 = acc02 + bv.z, o03 = acc03 + bv.w;
        float o10 = acc10 + bv.x, o11 = acc11 + bv.y, o12 = acc12 + bv.z, o13 = acc13 + bv.w;
        if constexpr (POST == 1) {
            o00 = tanhf(o00); o01 = tanhf(o01); o02 = tanhf(o02); o03 = tanhf(o03);
            o10 = tanhf(o10); o11 = tanhf(o11); o12 = tanhf(o12); o13 = tanhf(o13);
        }
        const int row0 = row_base + r0;
        const int row1 = row0 + 8;
        if (row0 < nrows) {
            *(float4*)(out + (size_t)row0 * DD + c0) = make_float4(o00,o01,o02,o03);
            if constexpr (BNSTAT != 0) {
                bsum0 += o00; bsum1 += o01; bsum2 += o02; bsum3 += o03;
                bsq0 += o00*o00; bsq1 += o01*o01; bsq2 += o02*o02; bsq3 += o03*o03;
            }
        }
        if (row1 < nrows) {
            *(float4*)(out + (size_t)row1 * DD + c0) = make_float4(o10,o11,o12,o13);
            if constexpr (BNSTAT != 0) {
                bsum0 += o10; bsum1 += o11; bsum2 += o12; bsum3 += o13;
                bsq0 += o10*o10; bsq1 += o11*o11; bsq2 += o12*o12; bsq3 += o13*o13;
            }
        }
        __syncthreads();
    }

    if constexpr (BNSTAT != 0) {
        atomicAdd(&ps[c0+0], bsum0); atomicAdd(&ps[c0+1], bsum1);
        atomicAdd(&ps[c0+2], bsum2); atomicAdd(&ps[c0+3], bsum3);
        atomicAdd(&psq[c0+0], bsq0); atomicAdd(&psq[c0+1], bsq1);
        atomicAdd(&psq[c0+2], bsq2); atomicAdd(&psq[c0+3], bsq3);
        __syncthreads();
        if (tid < DD) {
            atomicAdd(&bnsum[tid], ps[tid]);
            atomicAdd(&bnsumsq[tid], psq[tid]);
        }
    }
}

// =====================================================================
// Edge pass: per edge e (one wave per edge, grid-stride):
//   ea_n = edge_attr[e] / (||.|| + 1e-8)
//   m    = tanh(h[src] + ea_n @ W_edge + b_edge)       (128, 2 ch/lane)
//   l    = m . att_vec ;  w = exp(l)
//   wexp[e] = w; denom[dst] += w; U[dst] += w*m        (atomics)
// =====================================================================
__global__ __launch_bounds__(256) void edge_kernel(
    const float* __restrict__ ea, const int* __restrict__ src,
    const int* __restrict__ dst,
    const float* __restrict__ Wedge, const float* __restrict__ bedge,
    const float* __restrict__ att, const float* __restrict__ h,
    float* __restrict__ U, float* __restrict__ denom,
    float* __restrict__ wexp, int nedges)
{
    __shared__ float We[DEE * DD];   // 16 KB
    __shared__ float be[DD], av[DD];
    const int tid = threadIdx.x;
    for (int i = tid; i < DEE * DD / 4; i += 256)
        ((float4*)We)[i] = ((const float4*)Wedge)[i];
    if (tid < DD) { be[tid] = bedge[tid]; av[tid] = att[tid]; }
    __syncthreads();

    const int lane = tid & 63;
    const int wid  = (blockIdx.x * 256 + tid) >> 6;
    const int nw   = (gridDim.x * 256) >> 6;

    for (int e = wid; e < nedges; e += nw) {
        float v = 0.f;
        if (lane < DEE) v = ea[(size_t)e * DEE + lane];
        float ss = v * v;
        ss += __shfl_xor(ss, 32); ss += __shfl_xor(ss, 16);
        ss += __shfl_xor(ss, 8);  ss += __shfl_xor(ss, 4);
        ss += __shfl_xor(ss, 2);  ss += __shfl_xor(ss, 1);
        const float inv = 1.0f / (sqrtf(ss) + 1e-8f);

        float p0 = be[lane], p1 = be[lane + 64];
        #pragma unroll
        for (int k = 0; k < DEE; k++) {
            const float ek = __shfl(v, k) * inv;
            p0 += ek * We[k * DD + lane];
            p1 += ek * We[k * DD + lane + 64];
        }

        const int s  = src[e];
        const int dn = dst[e];
        const float m0 = tanhf(h[(size_t)s * DD + lane]      + p0);
        const float m1 = tanhf(h[(size_t)s * DD + lane + 64] + p1);

        float l = m0 * av[lane] + m1 * av[lane + 64];
        l += __shfl_xor(l, 32); l += __shfl_xor(l, 16);
        l += __shfl_xor(l, 8);  l += __shfl_xor(l, 4);
        l += __shfl_xor(l, 2);  l += __shfl_xor(l, 1);
        const float w = expf(l);   // bounded: |l| <= ||att||_1 ~ 20

        if (lane == 0) {
            wexp[e] = w;
            atomicAdd(&denom[dn], w);
        }
        atomicAdd(&U[(size_t)dn * DD + lane],      w * m0);
        atomicAdd(&U[(size_t)dn * DD + lane + 64], w * m1);
    }
}

// attn[e] = wexp[e] / (denom[dst[e]] + 1e-16)
__global__ __launch_bounds__(256) void attn_kernel(
    const float* __restrict__ wexp, const int* __restrict__ dst,
    const float* __restrict__ denom, float* __restrict__ attn_out, int nedges)
{
    const int i = blockIdx.x * 256 + threadIdx.x;
    if (i < nedges) attn_out[i] = wexp[i] / (denom[dst[i]] + 1e-16f);
}

// batch-norm finalize: scale/shift per channel
__global__ void bnfin_kernel(
    const float* __restrict__ bnsum, const float* __restrict__ bnsumsq,
    const float* __restrict__ gamma, const float* __restrict__ beta,
    float* __restrict__ scale, float* __restrict__ shift, float invn)
{
    const int c = threadIdx.x;
    if (c < DD) {
        const float mu  = bnsum[c] * invn;
        const float var = bnsumsq[c] * invn - mu * mu;
        const float a   = gamma[c] * rsqrtf(var + 1e-5f);
        scale[c] = a;
        shift[c] = beta[c] - mu * a;
    }
}

extern "C" void kernel_launch(void* const* d_in, const int* in_sizes, int n_in,
                              void* d_out, int out_size, void* d_ws, size_t ws_size,
                              hipStream_t stream) {
    const float* x      = (const float*)d_in[0];
    const float* eattr  = (const float*)d_in[1];
    const int*   ei     = (const int*)  d_in[2];
    const float* W_init = (const float*)d_in[3];
    const float* W_edge = (const float*)d_in[4];
    const float* b_edge = (const float*)d_in[5];
    const float* attv   = (const float*)d_in[6];
    const float* eps    = (const float*)d_in[7];
    const float* W_u1   = (const float*)d_in[8];
    const float* b_u1   = (const float*)d_in[9];
    const float* W_u2   = (const float*)d_in[10];
    const float* b_u2   = (const float*)d_in[11];
    const float* W_o1   = (const float*)d_in[12];
    const float* b_o1   = (const float*)d_in[13];
    const float* gamma  = (const float*)d_in[14];
    const float* beta   = (const float*)d_in[15];
    const float* W_o2   = (const float*)d_in[16];
    const float* b_o2   = (const float*)d_in[17];

    const int N = in_sizes[0] / DD;     // 50000
    const int E = in_sizes[2] / 2;      // 800000
    const size_t ND = (size_t)N * DD;

    float* out      = (float*)d_out;
    float* attn_out = out + ND;

    // workspace layout (floats): h | U | t | denom | wexp | bn(4x128)
    float* ws    = (float*)d_ws;
    float* h     = ws;
    float* U     = ws + ND;
    float* tbuf  = ws + 2 * ND;
    float* denom = ws + 3 * ND;
    float* wexp  = denom + N;
    float* bnsum = wexp + E;
    float* bnsq  = bnsum + DD;
    float* bnsc  = bnsq + DD;
    float* bnsh  = bnsc + DD;
    float* ubuf  = U;    // U dead after GIN-pre GEMM
    float* zbuf  = h;    // h dead after GIN-pre GEMM

    const int* srcp = ei;
    const int* dstp = ei + E;

    hipMemsetAsync(U, 0, ND * sizeof(float), stream);
    hipMemsetAsync(denom, 0, (size_t)N * sizeof(float), stream);
    hipMemsetAsync(bnsum, 0, 2 * DD * sizeof(float), stream);

    const int gemm_grid = 512;   // 2 blocks/CU resident, grid-stride over 3125 tiles
    dim3 blk(256);

    // h = x @ W_init
    gemm128_kernel<0,0,0><<<gemm_grid, blk, 0, stream>>>(
        x, W_init, nullptr, h, N,
        nullptr, nullptr, nullptr, nullptr, nullptr, nullptr, nullptr);

    // edge pass
    edge_kernel<<<2048, blk, 0, stream>>>(
        eattr, srcp, dstp, W_edge, b_edge, attv, h, U, denom, wexp, E);

    // attn output
    attn_kernel<<<(E + 255) / 256, blk, 0, stream>>>(wexp, dstp, denom, attn_out, E);

    // t = tanh(((1+eps)h + U/denom) @ W_u1 + b_u1)
    gemm128_kernel<1,1,0><<<gemm_grid, blk, 0, stream>>>(
        h, W_u1, b_u1, tbuf, N,
        U, denom, eps, nullptr, nullptr, nullptr, nullptr);

    // u = t @ W_u2 + b_u2
    gemm128_kernel<0,0,0><<<gemm_grid, blk, 0, stream>>>(
        tbuf, W_u2, b_u2, ubuf, N,
        nullptr, nullptr, nullptr, nullptr, nullptr, nullptr, nullptr);

    // z = u @ W_o1 + b_o1  (+ BN stats)
    gemm128_kernel<0,0,1><<<gemm_grid, blk, 0, stream>>>(
        ubuf, W_o1, b_o1, zbuf, N,
        nullptr, nullptr, nullptr, nullptr, nullptr, bnsum, bnsq);

    // bn finalize
    bnfin_kernel<<<1, DD, 0, stream>>>(bnsum, bnsq, gamma, beta, bnsc, bnsh, 1.0f / (float)N);

    // out = tanh(z*a+b) @ W_o2 + b_o2
    gemm128_kernel<2,0,0><<<gemm_grid, blk, 0, stream>>>(
        zbuf, W_o2, b_o2, out, N,
        nullptr, nullptr, nullptr, bnsc, bnsh, nullptr, nullptr);
}